// Round 16
// baseline (59.868 us; speedup 1.0000x reference)
//
#include <hip/hip_runtime.h>
#include <math.h>

typedef short short8 __attribute__((ext_vector_type(8)));
typedef float f32x4 __attribute__((ext_vector_type(4)));

#define B_N 2048
#define NKM 9
#define CP 512          // C*4, cp = c*4 + p  (p fastest)
#define KU 128          // MUL
#define INV_SQRT_MUL 0.08838834764831845f   // 1/sqrt(128)
#define INV_SQRT_4C  0.04419417382415922f   // 1/sqrt(512)

// persistent device scratch; fully rewritten every launch before any read
__device__ ushort g_xb1[NKM * B_N * KU];          // [km][b][u] bf16
__device__ ushort g_xb2[NKM * B_N * KU];
__device__ ushort g_W1bt[3 * CP * KU];            // [l][cp][u] bf16, * 1/sqrt(128)
__device__ ushort g_W2bt[3 * CP * KU];
__device__ ushort g_Woutbt[3 * KU * CP];          // [l][u][cp] bf16, * 1/sqrt(512)
__device__ ushort g_c1b[(size_t)B_N * NKM * CP];  // [b][km][cp] bf16
__device__ ushort g_c2b[(size_t)B_N * NKM * CP];
__device__ ushort g_cb[(size_t)B_N * NKM * CP];   // c_out, [b][km][cp] bf16

__device__ __forceinline__ ushort f2b(float f) {
    uint u = __float_as_uint(f);
    uint r = (u + 0x7fffu + ((u >> 16) & 1u)) >> 16;   // RNE
    return (ushort)r;
}
__device__ __forceinline__ float pk_lo(uint u) { return __uint_as_float(u << 16); }
__device__ __forceinline__ float pk_hi(uint u) { return __uint_as_float(u & 0xffff0000u); }
__device__ __forceinline__ int l_of_km(int km) { return (km >= 4) ? 2 : (km >= 1 ? 1 : 0); }

// ---------------------------------------------------------------------------
// Gaunt tensor (real orthonormal SH, l<=2): closed form; per-k constexpr
// sub-tables -> constexpr loop bounds -> full unroll -> literal reg indices.
// ---------------------------------------------------------------------------
__host__ __device__ constexpr int lof(int n) { return n >= 4 ? 2 : (n >= 1 ? 1 : 0); }
__host__ __device__ constexpr int mof(int n) { int l = lof(n); return n - l * l - l; }
__host__ __device__ constexpr bool gaunt_nz(int a, int b, int c) {
    int la = lof(a), lb = lof(b), lc = lof(c);
    if ((la + lb + lc) & 1) return false;
    if (lc > la + lb || la > lb + lc || lb > lc + la) return false;
    int ma = mof(a), mb = mof(b), mc = mof(c);
    int neg = (ma < 0) + (mb < 0) + (mc < 0);
    if (neg & 1) return false;
    int A = ma < 0 ? -ma : ma, Bm = mb < 0 ? -mb : mb, Cm = mc < 0 ? -mc : mc;
    return (A + Bm == Cm) || (Bm + Cm == A) || (Cm + A == Bm);
}
__host__ __device__ constexpr float gaunt_val(int a, int b, int c) {
    int x = a, y = b, z = c, t = 0;
    if (x > y) { t = x; x = y; y = t; }
    if (y > z) { t = y; y = z; z = t; }
    if (x > y) { t = x; x = y; y = t; }
    const float C00 = 0.28209479177387814f;   // 1/(2*sqrt(pi))
    const float A_  = 0.12615662610100802f;
    const float B_  = 0.25231325220201604f;
    const float C_  = 0.21850968611841584f;
    const float D_  = 0.18022375157286857f;
    const float E_  = 0.09011187578643429f;
    const float F_  = 0.15607834722743988f;
    if (x == 0) return C00;
    if (y <= 3) {
        if (z == 6) return (y == 2) ? B_ : -A_;
        if (z == 8) return (x == 1) ? -C_ : C_;
        return C_;
    }
    if (x == 4) return (y == 4) ? -D_ : F_;
    if (x == 5) return (z == 6) ? E_ : -F_;
    if (x == 6) return (y == 6) ? D_ : ((y == 7) ? E_ : -D_);
    return F_;
}
struct KEnt { int i, j; float v; };
struct KTab { KEnt e[16]; int n; };
__host__ __device__ constexpr KTab make_kt(int kk) {
    KTab t{};
    for (int i = 0; i < 9; ++i)
        for (int j = 0; j < 9; ++j)
            if (gaunt_nz(kk, i, j)) {
                t.e[t.n].i = i; t.e[t.n].j = j; t.e[t.n].v = gaunt_val(kk, i, j);
                ++t.n;
            }
    return t;
}

// c-pair variant: unit0 = words (.x,.y), unit1 = words (.z,.w) of each uint4
template <int KK>
__device__ __forceinline__ void gaunt_pair(const uint4 (&r1)[9], const uint4 (&r2)[9],
                                           ushort* __restrict__ w) {
    constexpr KTab T = make_kt(KK);
    float u0o0 = 0.f, u0o1 = 0.f, u0o2 = 0.f, u0o3 = 0.f;
    float u1o0 = 0.f, u1o1 = 0.f, u1o2 = 0.f, u1o3 = 0.f;
    #pragma unroll
    for (int e = 0; e < T.n; ++e) {        // constexpr bound -> full unroll
        const int   i = T.e[e].i, j = T.e[e].j;
        const float g = T.e[e].v;
        {   // unit 0 (even c)
            float a0 = pk_lo(r1[i].x), a1 = pk_hi(r1[i].x);
            float a2 = pk_lo(r1[i].y), a3 = pk_hi(r1[i].y);
            float d0 = pk_lo(r2[j].x), d1 = pk_hi(r2[j].x);
            float d2 = pk_lo(r2[j].y), d3 = pk_hi(r2[j].y);
            u0o0 = fmaf(g, a0 * d0, u0o0);
            u0o1 = fmaf(g, fmaf(a2, d3, -(a3 * d2)), u0o1);
            u0o2 = fmaf(g, fmaf(a3, d1, -(a1 * d3)), u0o2);
            u0o3 = fmaf(g, fmaf(a1, d2, -(a2 * d1)), u0o3);
        }
        {   // unit 1 (odd c)
            float a0 = pk_lo(r1[i].z), a1 = pk_hi(r1[i].z);
            float a2 = pk_lo(r1[i].w), a3 = pk_hi(r1[i].w);
            float d0 = pk_lo(r2[j].z), d1 = pk_hi(r2[j].z);
            float d2 = pk_lo(r2[j].w), d3 = pk_hi(r2[j].w);
            u1o0 = fmaf(g, a0 * d0, u1o0);
            u1o1 = fmaf(g, fmaf(a2, d3, -(a3 * d2)), u1o1);
            u1o2 = fmaf(g, fmaf(a3, d1, -(a1 * d3)), u1o2);
            u1o3 = fmaf(g, fmaf(a1, d2, -(a2 * d1)), u1o3);
        }
    }
    uint4 st;
    st.x = (uint)f2b(u0o0) | ((uint)f2b(u0o1) << 16);
    st.y = (uint)f2b(u0o2) | ((uint)f2b(u0o3) << 16);
    st.z = (uint)f2b(u1o0) | ((uint)f2b(u1o1) << 16);
    st.w = (uint)f2b(u1o2) | ((uint)f2b(u1o3) << 16);
    *(uint4*)&w[KK * CP] = st;
}

// ---------------------------------------------------------------------------
// prep_combined (validated):
//   blocks [0, B_N):        x transpose->bf16 for row b, + zero out tail cols
//   blocks [B_N, B_N+768):  W1/W2/Wout bf16 repack with scales folded in
// ---------------------------------------------------------------------------
__global__ __launch_bounds__(256) void prep_kernel(const float* __restrict__ x1,
                                                   const float* __restrict__ x2,
                                                   const float* __restrict__ W1,
                                                   const float* __restrict__ W2,
                                                   const float* __restrict__ Wout,
                                                   float* __restrict__ out) {
    int bid = blockIdx.x, tid = threadIdx.x;
    if (bid >= B_N) {
        int idx = (bid - B_N) * 256 + tid;       // < 3*512*128 = 196608
        int l = idx >> 16;
        int r = idx & 65535;
        {   // W1bt/W2bt [l][cp][u] <- W[l][u][cp]
            int cp = r >> 7, u = r & 127;
            size_t src = (size_t)l * 65536 + (size_t)u * 512 + cp;
            g_W1bt[idx] = f2b(W1[src] * INV_SQRT_MUL);
            g_W2bt[idx] = f2b(W2[src] * INV_SQRT_MUL);
        }
        {   // Woutbt [l][u][cp] <- Wout[l][cp][u]
            int u = r >> 9, cp = r & 511;
            g_Woutbt[idx] = f2b(Wout[(size_t)l * 65536 + (size_t)cp * 128 + u] * INV_SQRT_4C);
        }
        return;
    }
    int b = bid;
    __shared__ float L1[2048], L2[2048];
    const float4* r1 = (const float4*)(x1 + (size_t)b * 2048);
    const float4* r2 = (const float4*)(x2 + (size_t)b * 2048);
    #pragma unroll
    for (int i = 0; i < 2; ++i) {
        int q = i * 256 + tid;
        *(float4*)&L1[q * 4] = r1[q];
        *(float4*)&L2[q * 4] = r2[q];
    }
    // zero the l=3 output tail for this row: cols [1152,2048) = 224 float4
    float4 z = make_float4(0.f, 0.f, 0.f, 0.f);
    if (tid < 224) *(float4*)&out[(size_t)b * 2048 + 1152 + tid * 4] = z;
    __syncthreads();
    #pragma unroll
    for (int i = 0; i < 9; ++i) {
        int e = i * 256 + tid;                    // < 2304
        int field = e >= 1152;
        int r = e - field * 1152;
        int km = r >> 7, u = r & 127;
        int l = l_of_km(km);
        int col = l * l * 128 + u * (2 * l + 1) + (km - l * l);
        float v = field ? L2[col] : L1[col];
        ushort* dst = field ? g_xb2 : g_xb1;
        dst[(size_t)km * (B_N * KU) + (size_t)b * KU + u] = f2b(v);
    }
}

// ---------------------------------------------------------------------------
// gemm_c (validated) + XCD-chunked swizzle (neutral but harmless)
// ---------------------------------------------------------------------------
__global__ __launch_bounds__(256) void gemm_c_kernel() {
    __shared__ ushort As[64 * 128];
    __shared__ ushort Bs[64 * 128];
    int tid = threadIdx.x;
    int bid = blockIdx.x;
    int xcd = bid & 7, slot = bid >> 3;     // slot 0..575
    int btl = slot & 3;
    int rem = slot >> 2;                    // 0..143
    int z  = rem >> 3;                      // 0..17
    int nt = rem & 7;                       // 0..7
    int b0 = (xcd * 4 + btl) * 64, n0 = nt * 64;

    int field = (z >= NKM);
    int km = field ? z - NKM : z;
    int l = l_of_km(km);
    const ushort* xa = (field ? g_xb2 : g_xb1) + (size_t)km * (B_N * KU);
    const ushort* wb = (field ? g_W2bt : g_W1bt) + (size_t)l * 65536;
    ushort* cdst = field ? g_c2b : g_c1b;

    #pragma unroll
    for (int it = 0; it < 4; ++it) {
        int i = it * 256 + tid;            // 16B chunk id, 0..1023
        int row = i >> 4, kg = i & 15;
        int dst = row * 128 + ((kg ^ (row & 7)) << 3);
        *(short8*)&As[dst] = *(const short8*)&xa[(size_t)(b0 + row) * KU + (kg << 3)];
        *(short8*)&Bs[dst] = *(const short8*)&wb[(size_t)(n0 + row) * KU + (kg << 3)];
    }
    __syncthreads();

    int lane = tid & 63, wid = tid >> 6, wr = wid >> 1, wc = wid & 1;
    f32x4 acc[2][2];
    #pragma unroll
    for (int i = 0; i < 2; ++i)
        #pragma unroll
        for (int j = 0; j < 2; ++j) acc[i][j] = (f32x4){0.f, 0.f, 0.f, 0.f};

    #pragma unroll
    for (int ks = 0; ks < 4; ++ks) {
        int kg = ks * 4 + (lane >> 4);
        short8 a[2], b[2];
        #pragma unroll
        for (int i = 0; i < 2; ++i) {
            int row = wr * 32 + i * 16 + (lane & 15);
            a[i] = *(const short8*)&As[row * 128 + ((kg ^ (row & 7)) << 3)];
        }
        #pragma unroll
        for (int j = 0; j < 2; ++j) {
            int row = wc * 32 + j * 16 + (lane & 15);
            b[j] = *(const short8*)&Bs[row * 128 + ((kg ^ (row & 7)) << 3)];
        }
        #pragma unroll
        for (int i = 0; i < 2; ++i)
            #pragma unroll
            for (int j = 0; j < 2; ++j)
                acc[i][j] = __builtin_amdgcn_mfma_f32_16x16x32_bf16(a[i], b[j], acc[i][j], 0, 0, 0);
    }

    #pragma unroll
    for (int i = 0; i < 2; ++i)
        #pragma unroll
        for (int j = 0; j < 2; ++j)
            #pragma unroll
            for (int r = 0; r < 4; ++r) {
                int row = b0 + wr * 32 + i * 16 + ((lane >> 4) << 2) + r;
                int col = n0 + wc * 32 + j * 16 + (lane & 15);
                cdst[((size_t)row * NKM + km) * CP + col] = f2b(acc[i][j][r]);
            }
}

// ---------------------------------------------------------------------------
// middle v9: thread = (b, c-pair). 18 x 16B loads + 9 x 16B stores covering
// TWO units -> 13.5 VMEM ops/unit (halved vs v8), all 1KB/wave coalesced.
// Inputs stay PACKED (72 uints); lazy 1-VALU unpack; per-k constexpr tables;
// store per-k -> only 8 f32 accumulators live. No launch_bounds VGPR cap.
// grid 512 blocks.
// ---------------------------------------------------------------------------
__global__ __launch_bounds__(256) void middle_kernel() {
    int idx = blockIdx.x * 256 + threadIdx.x;   // < 2048*64
    int b = idx >> 6, cq = idx & 63;            // cq = pair of adjacent c
    const ushort* s1 = g_c1b + (size_t)b * (NKM * CP) + cq * 8;
    const ushort* s2 = g_c2b + (size_t)b * (NKM * CP) + cq * 8;

    uint4 r1[9], r2[9];
    #pragma unroll
    for (int k = 0; k < 9; ++k) {
        r1[k] = *(const uint4*)&s1[k * CP];
        r2[k] = *(const uint4*)&s2[k * CP];
    }

    ushort* w = g_cb + (size_t)b * (NKM * CP) + cq * 8;
    gaunt_pair<0>(r1, r2, w);
    gaunt_pair<1>(r1, r2, w);
    gaunt_pair<2>(r1, r2, w);
    gaunt_pair<3>(r1, r2, w);
    gaunt_pair<4>(r1, r2, w);
    gaunt_pair<5>(r1, r2, w);
    gaunt_pair<6>(r1, r2, w);
    gaunt_pair<7>(r1, r2, w);
    gaunt_pair<8>(r1, r2, w);
}

// ---------------------------------------------------------------------------
// out_gemm (validated) + XCD swizzle
// ---------------------------------------------------------------------------
__global__ __launch_bounds__(256) void out_gemm_kernel(float* __restrict__ out) {
    __shared__ ushort As[64 * 128];
    __shared__ ushort Bs[64 * 128];
    int tid = threadIdx.x;
    int bid = blockIdx.x;
    int xcd = bid & 7, s = bid >> 3;        // s 0..71
    int km = s >> 3;                        // 0..8
    int r9 = s & 7;
    int bx = xcd * 4 + (r9 >> 1);
    int by = r9 & 1;

    int l = l_of_km(km);
    int mi = km - l * l, d = 2 * l + 1, OFF = 128 * l * l;
    int b0 = bx * 64, u0 = by * 64;

    int lane = tid & 63, wid = tid >> 6, wr = wid >> 1, wc = wid & 1;
    f32x4 acc[2][2];
    #pragma unroll
    for (int i = 0; i < 2; ++i)
        #pragma unroll
        for (int j = 0; j < 2; ++j) acc[i][j] = (f32x4){0.f, 0.f, 0.f, 0.f};

    for (int kc = 0; kc < 4; ++kc) {
        #pragma unroll
        for (int it = 0; it < 4; ++it) {
            int i = it * 256 + tid;
            int row = i >> 4, kg = i & 15;
            int dst = row * 128 + ((kg ^ (row & 7)) << 3);
            *(short8*)&As[dst] = *(const short8*)&g_cb[(size_t)(b0 + row) * (NKM * CP)
                                                       + (size_t)km * CP + kc * 128 + (kg << 3)];
            *(short8*)&Bs[dst] = *(const short8*)&g_Woutbt[(size_t)l * 65536
                                                       + (size_t)(u0 + row) * CP + kc * 128 + (kg << 3)];
        }
        __syncthreads();
        #pragma unroll
        for (int ks = 0; ks < 4; ++ks) {
            int kg = ks * 4 + (lane >> 4);
            short8 a[2], b[2];
            #pragma unroll
            for (int i = 0; i < 2; ++i) {
                int row = wr * 32 + i * 16 + (lane & 15);
                a[i] = *(const short8*)&As[row * 128 + ((kg ^ (row & 7)) << 3)];
            }
            #pragma unroll
            for (int j = 0; j < 2; ++j) {
                int row = wc * 32 + j * 16 + (lane & 15);
                b[j] = *(const short8*)&Bs[row * 128 + ((kg ^ (row & 7)) << 3)];
            }
            #pragma unroll
            for (int i = 0; i < 2; ++i)
                #pragma unroll
                for (int j = 0; j < 2; ++j)
                    acc[i][j] = __builtin_amdgcn_mfma_f32_16x16x32_bf16(a[i], b[j], acc[i][j], 0, 0, 0);
        }
        __syncthreads();
    }

    #pragma unroll
    for (int i = 0; i < 2; ++i)
        #pragma unroll
        for (int j = 0; j < 2; ++j)
            #pragma unroll
            for (int r = 0; r < 4; ++r) {
                int row = b0 + wr * 32 + i * 16 + ((lane >> 4) << 2) + r;
                int u   = u0 + wc * 32 + j * 16 + (lane & 15);
                out[(size_t)row * 2048 + OFF + u * d + mi] = acc[i][j][r];
            }
}

// ---------------------------------------------------------------------------
extern "C" void kernel_launch(void* const* d_in, const int* in_sizes, int n_in,
                              void* d_out, int out_size, void* d_ws, size_t ws_size,
                              hipStream_t stream) {
    const float* x1   = (const float*)d_in[0];
    const float* x2   = (const float*)d_in[1];
    const float* W1   = (const float*)d_in[2];
    const float* W2   = (const float*)d_in[3];
    const float* Wout = (const float*)d_in[4];
    float* out = (float*)d_out;

    prep_kernel<<<B_N + 768, 256, 0, stream>>>(x1, x2, W1, W2, Wout, out);
    gemm_c_kernel<<<4608, 256, 0, stream>>>();
    middle_kernel<<<512, 256, 0, stream>>>();
    out_gemm_kernel<<<576, 256, 0, stream>>>(out);
}

// Round 17
// 55.813 us; speedup vs baseline: 1.0727x; 1.0727x over previous
//
#include <hip/hip_runtime.h>
#include <math.h>

typedef short short8 __attribute__((ext_vector_type(8)));
typedef float f32x4 __attribute__((ext_vector_type(4)));

#define B_N 2048
#define NKM 9
#define CP 512          // C*4, cp = c*4 + p  (p fastest)
#define KU 128          // MUL
#define INV_SQRT_MUL 0.08838834764831845f   // 1/sqrt(128)
#define INV_SQRT_4C  0.04419417382415922f   // 1/sqrt(512)

// persistent device scratch; fully rewritten every launch before any read
__device__ ushort g_xb1[NKM * B_N * KU];          // [km][b][u] bf16
__device__ ushort g_xb2[NKM * B_N * KU];
__device__ ushort g_W1bt[3 * CP * KU];            // [l][cp][u] bf16, * 1/sqrt(128)
__device__ ushort g_W2bt[3 * CP * KU];
__device__ ushort g_Woutbt[3 * KU * CP];          // [l][u][cp] bf16, * 1/sqrt(512)
__device__ ushort g_c1b[(size_t)B_N * NKM * CP];  // [b][km][cp] bf16
__device__ ushort g_c2b[(size_t)B_N * NKM * CP];
__device__ ushort g_cb[(size_t)B_N * NKM * CP];   // c_out, [b][km][cp] bf16

__device__ __forceinline__ ushort f2b(float f) {
    uint u = __float_as_uint(f);
    uint r = (u + 0x7fffu + ((u >> 16) & 1u)) >> 16;   // RNE
    return (ushort)r;
}
__device__ __forceinline__ float pk_lo(uint u) { return __uint_as_float(u << 16); }
__device__ __forceinline__ float pk_hi(uint u) { return __uint_as_float(u & 0xffff0000u); }
__device__ __forceinline__ int l_of_km(int km) { return (km >= 4) ? 2 : (km >= 1 ? 1 : 0); }

// ---------------------------------------------------------------------------
// Gaunt tensor (real orthonormal SH, l<=2): closed form; per-k constexpr
// sub-tables -> constexpr loop bounds -> full unroll -> literal reg indices.
// ---------------------------------------------------------------------------
__host__ __device__ constexpr int lof(int n) { return n >= 4 ? 2 : (n >= 1 ? 1 : 0); }
__host__ __device__ constexpr int mof(int n) { int l = lof(n); return n - l * l - l; }
__host__ __device__ constexpr bool gaunt_nz(int a, int b, int c) {
    int la = lof(a), lb = lof(b), lc = lof(c);
    if ((la + lb + lc) & 1) return false;
    if (lc > la + lb || la > lb + lc || lb > lc + la) return false;
    int ma = mof(a), mb = mof(b), mc = mof(c);
    int neg = (ma < 0) + (mb < 0) + (mc < 0);
    if (neg & 1) return false;
    int A = ma < 0 ? -ma : ma, Bm = mb < 0 ? -mb : mb, Cm = mc < 0 ? -mc : mc;
    return (A + Bm == Cm) || (Bm + Cm == A) || (Cm + A == Bm);
}
__host__ __device__ constexpr float gaunt_val(int a, int b, int c) {
    int x = a, y = b, z = c, t = 0;
    if (x > y) { t = x; x = y; y = t; }
    if (y > z) { t = y; y = z; z = t; }
    if (x > y) { t = x; x = y; y = t; }
    const float C00 = 0.28209479177387814f;   // 1/(2*sqrt(pi))
    const float A_  = 0.12615662610100802f;
    const float B_  = 0.25231325220201604f;
    const float C_  = 0.21850968611841584f;
    const float D_  = 0.18022375157286857f;
    const float E_  = 0.09011187578643429f;
    const float F_  = 0.15607834722743988f;
    if (x == 0) return C00;
    if (y <= 3) {
        if (z == 6) return (y == 2) ? B_ : -A_;
        if (z == 8) return (x == 1) ? -C_ : C_;
        return C_;
    }
    if (x == 4) return (y == 4) ? -D_ : F_;
    if (x == 5) return (z == 6) ? E_ : -F_;
    if (x == 6) return (y == 6) ? D_ : ((y == 7) ? E_ : -D_);
    return F_;
}
struct KEnt { int i, j; float v; };
struct KTab { KEnt e[16]; int n; };
__host__ __device__ constexpr KTab make_kt(int kk) {
    KTab t{};
    for (int i = 0; i < 9; ++i)
        for (int j = 0; j < 9; ++j)
            if (gaunt_nz(kk, i, j)) {
                t.e[t.n].i = i; t.e[t.n].j = j; t.e[t.n].v = gaunt_val(kk, i, j);
                ++t.n;
            }
    return t;
}

template <int KK>
__device__ __forceinline__ void gaunt_kk(const uint (&p1)[2][9], const uint (&p2)[2][9],
                                         ushort* __restrict__ w) {
    constexpr KTab T = make_kt(KK);
    float o0 = 0.f, o1 = 0.f, o2 = 0.f, o3 = 0.f;
    #pragma unroll
    for (int e = 0; e < T.n; ++e) {        // constexpr bound -> full unroll
        const int   i = T.e[e].i, j = T.e[e].j;
        const float g = T.e[e].v;
        float a0 = pk_lo(p1[0][i]), a1 = pk_hi(p1[0][i]);
        float a2 = pk_lo(p1[1][i]), a3 = pk_hi(p1[1][i]);
        float d0 = pk_lo(p2[0][j]), d1 = pk_hi(p2[0][j]);
        float d2 = pk_lo(p2[1][j]), d3 = pk_hi(p2[1][j]);
        o0 = fmaf(g, a0 * d0, o0);
        o1 = fmaf(g, fmaf(a2, d3, -(a3 * d2)), o1);
        o2 = fmaf(g, fmaf(a3, d1, -(a1 * d3)), o2);
        o3 = fmaf(g, fmaf(a1, d2, -(a2 * d1)), o3);
    }
    uint2 st;
    st.x = (uint)f2b(o0) | ((uint)f2b(o1) << 16);
    st.y = (uint)f2b(o2) | ((uint)f2b(o3) << 16);
    *(uint2*)&w[KK * CP] = st;
}

// ---------------------------------------------------------------------------
// prep_combined (validated):
//   blocks [0, B_N):        x transpose->bf16 for row b, + zero out tail cols
//   blocks [B_N, B_N+768):  W1/W2/Wout bf16 repack with scales folded in
// ---------------------------------------------------------------------------
__global__ __launch_bounds__(256) void prep_kernel(const float* __restrict__ x1,
                                                   const float* __restrict__ x2,
                                                   const float* __restrict__ W1,
                                                   const float* __restrict__ W2,
                                                   const float* __restrict__ Wout,
                                                   float* __restrict__ out) {
    int bid = blockIdx.x, tid = threadIdx.x;
    if (bid >= B_N) {
        int idx = (bid - B_N) * 256 + tid;       // < 3*512*128 = 196608
        int l = idx >> 16;
        int r = idx & 65535;
        {   // W1bt/W2bt [l][cp][u] <- W[l][u][cp]
            int cp = r >> 7, u = r & 127;
            size_t src = (size_t)l * 65536 + (size_t)u * 512 + cp;
            g_W1bt[idx] = f2b(W1[src] * INV_SQRT_MUL);
            g_W2bt[idx] = f2b(W2[src] * INV_SQRT_MUL);
        }
        {   // Woutbt [l][u][cp] <- Wout[l][cp][u]
            int u = r >> 9, cp = r & 511;
            g_Woutbt[idx] = f2b(Wout[(size_t)l * 65536 + (size_t)cp * 128 + u] * INV_SQRT_4C);
        }
        return;
    }
    int b = bid;
    __shared__ float L1[2048], L2[2048];
    const float4* r1 = (const float4*)(x1 + (size_t)b * 2048);
    const float4* r2 = (const float4*)(x2 + (size_t)b * 2048);
    #pragma unroll
    for (int i = 0; i < 2; ++i) {
        int q = i * 256 + tid;
        *(float4*)&L1[q * 4] = r1[q];
        *(float4*)&L2[q * 4] = r2[q];
    }
    // zero the l=3 output tail for this row: cols [1152,2048) = 224 float4
    float4 z = make_float4(0.f, 0.f, 0.f, 0.f);
    if (tid < 224) *(float4*)&out[(size_t)b * 2048 + 1152 + tid * 4] = z;
    __syncthreads();
    #pragma unroll
    for (int i = 0; i < 9; ++i) {
        int e = i * 256 + tid;                    // < 2304
        int field = e >= 1152;
        int r = e - field * 1152;
        int km = r >> 7, u = r & 127;
        int l = l_of_km(km);
        int col = l * l * 128 + u * (2 * l + 1) + (km - l * l);
        float v = field ? L2[col] : L1[col];
        ushort* dst = field ? g_xb2 : g_xb1;
        dst[(size_t)km * (B_N * KU) + (size_t)b * KU + u] = f2b(v);
    }
}

// ---------------------------------------------------------------------------
// gemm_c (r11 64x64 tile, validated) + XCD-chunked swizzle:
// XCD i owns b_tiles [4i, 4i+4) across all 18 z-planes and 8 n-tiles.
// 1D grid 4608 = 8 XCD * (4 bt * 18 z * 8 n).
// ---------------------------------------------------------------------------
__global__ __launch_bounds__(256) void gemm_c_kernel() {
    __shared__ ushort As[64 * 128];
    __shared__ ushort Bs[64 * 128];
    int tid = threadIdx.x;
    int bid = blockIdx.x;
    int xcd = bid & 7, slot = bid >> 3;     // slot 0..575
    int btl = slot & 3;
    int rem = slot >> 2;                    // 0..143
    int z  = rem >> 3;                      // 0..17
    int nt = rem & 7;                       // 0..7
    int b0 = (xcd * 4 + btl) * 64, n0 = nt * 64;

    int field = (z >= NKM);
    int km = field ? z - NKM : z;
    int l = l_of_km(km);
    const ushort* xa = (field ? g_xb2 : g_xb1) + (size_t)km * (B_N * KU);
    const ushort* wb = (field ? g_W2bt : g_W1bt) + (size_t)l * 65536;
    ushort* cdst = field ? g_c2b : g_c1b;

    #pragma unroll
    for (int it = 0; it < 4; ++it) {
        int i = it * 256 + tid;            // 16B chunk id, 0..1023
        int row = i >> 4, kg = i & 15;
        int dst = row * 128 + ((kg ^ (row & 7)) << 3);
        *(short8*)&As[dst] = *(const short8*)&xa[(size_t)(b0 + row) * KU + (kg << 3)];
        *(short8*)&Bs[dst] = *(const short8*)&wb[(size_t)(n0 + row) * KU + (kg << 3)];
    }
    __syncthreads();

    int lane = tid & 63, wid = tid >> 6, wr = wid >> 1, wc = wid & 1;
    f32x4 acc[2][2];
    #pragma unroll
    for (int i = 0; i < 2; ++i)
        #pragma unroll
        for (int j = 0; j < 2; ++j) acc[i][j] = (f32x4){0.f, 0.f, 0.f, 0.f};

    #pragma unroll
    for (int ks = 0; ks < 4; ++ks) {
        int kg = ks * 4 + (lane >> 4);
        short8 a[2], b[2];
        #pragma unroll
        for (int i = 0; i < 2; ++i) {
            int row = wr * 32 + i * 16 + (lane & 15);
            a[i] = *(const short8*)&As[row * 128 + ((kg ^ (row & 7)) << 3)];
        }
        #pragma unroll
        for (int j = 0; j < 2; ++j) {
            int row = wc * 32 + j * 16 + (lane & 15);
            b[j] = *(const short8*)&Bs[row * 128 + ((kg ^ (row & 7)) << 3)];
        }
        #pragma unroll
        for (int i = 0; i < 2; ++i)
            #pragma unroll
            for (int j = 0; j < 2; ++j)
                acc[i][j] = __builtin_amdgcn_mfma_f32_16x16x32_bf16(a[i], b[j], acc[i][j], 0, 0, 0);
    }

    #pragma unroll
    for (int i = 0; i < 2; ++i)
        #pragma unroll
        for (int j = 0; j < 2; ++j)
            #pragma unroll
            for (int r = 0; r < 4; ++r) {
                int row = b0 + wr * 32 + i * 16 + ((lane >> 4) << 2) + r;
                int col = n0 + wc * 32 + j * 16 + (lane & 15);
                cdst[((size_t)row * NKM + km) * CP + col] = f2b(acc[i][j][r]);
            }
}

// ---------------------------------------------------------------------------
// middle v8 (validated) + XCD swizzle: XCD i covers b in [256i, 256(i+1)).
// thread = (b,c): 18 x 8B loads + 9 x 8B stores, packed-uint storage,
// lazy unpack, constexpr per-k tables. 1D grid 1024.
// ---------------------------------------------------------------------------
__global__ __launch_bounds__(256) void middle_kernel() {
    int bid = blockIdx.x;
    int w9 = (bid & 7) * 128 + (bid >> 3);      // bijective: 1024 = 8 * 128
    int idx = w9 * 256 + threadIdx.x;           // < 2048*128
    int b = idx >> 7, c = idx & 127;
    const ushort* s1 = g_c1b + (size_t)b * (NKM * CP) + c * 4;
    const ushort* s2 = g_c2b + (size_t)b * (NKM * CP) + c * 4;

    uint p1[2][9], p2[2][9];
    #pragma unroll
    for (int k = 0; k < 9; ++k) {
        uint2 v1 = *(const uint2*)&s1[k * CP];
        uint2 v2 = *(const uint2*)&s2[k * CP];
        p1[0][k] = v1.x; p1[1][k] = v1.y;
        p2[0][k] = v2.x; p2[1][k] = v2.y;
    }

    ushort* w = g_cb + (size_t)b * (NKM * CP) + c * 4;
    gaunt_kk<0>(p1, p2, w);
    gaunt_kk<1>(p1, p2, w);
    gaunt_kk<2>(p1, p2, w);
    gaunt_kk<3>(p1, p2, w);
    gaunt_kk<4>(p1, p2, w);
    gaunt_kk<5>(p1, p2, w);
    gaunt_kk<6>(p1, p2, w);
    gaunt_kk<7>(p1, p2, w);
    gaunt_kk<8>(p1, p2, w);
}

// ---------------------------------------------------------------------------
// out_gemm (r11 64x64 tile, validated) + XCD swizzle: XCD i owns bx in
// [4i, 4i+4); both u-tiles of an A-tile co-located. 1D grid 576.
// ---------------------------------------------------------------------------
__global__ __launch_bounds__(256) void out_gemm_kernel(float* __restrict__ out) {
    __shared__ ushort As[64 * 128];
    __shared__ ushort Bs[64 * 128];
    int tid = threadIdx.x;
    int bid = blockIdx.x;
    int xcd = bid & 7, s = bid >> 3;        // s 0..71
    int km = s >> 3;                        // 0..8
    int r9 = s & 7;
    int bx = xcd * 4 + (r9 >> 1);
    int by = r9 & 1;

    int l = l_of_km(km);
    int mi = km - l * l, d = 2 * l + 1, OFF = 128 * l * l;
    int b0 = bx * 64, u0 = by * 64;

    int lane = tid & 63, wid = tid >> 6, wr = wid >> 1, wc = wid & 1;
    f32x4 acc[2][2];
    #pragma unroll
    for (int i = 0; i < 2; ++i)
        #pragma unroll
        for (int j = 0; j < 2; ++j) acc[i][j] = (f32x4){0.f, 0.f, 0.f, 0.f};

    for (int kc = 0; kc < 4; ++kc) {
        #pragma unroll
        for (int it = 0; it < 4; ++it) {
            int i = it * 256 + tid;
            int row = i >> 4, kg = i & 15;
            int dst = row * 128 + ((kg ^ (row & 7)) << 3);
            *(short8*)&As[dst] = *(const short8*)&g_cb[(size_t)(b0 + row) * (NKM * CP)
                                                       + (size_t)km * CP + kc * 128 + (kg << 3)];
            *(short8*)&Bs[dst] = *(const short8*)&g_Woutbt[(size_t)l * 65536
                                                       + (size_t)(u0 + row) * CP + kc * 128 + (kg << 3)];
        }
        __syncthreads();
        #pragma unroll
        for (int ks = 0; ks < 4; ++ks) {
            int kg = ks * 4 + (lane >> 4);
            short8 a[2], b[2];
            #pragma unroll
            for (int i = 0; i < 2; ++i) {
                int row = wr * 32 + i * 16 + (lane & 15);
                a[i] = *(const short8*)&As[row * 128 + ((kg ^ (row & 7)) << 3)];
            }
            #pragma unroll
            for (int j = 0; j < 2; ++j) {
                int row = wc * 32 + j * 16 + (lane & 15);
                b[j] = *(const short8*)&Bs[row * 128 + ((kg ^ (row & 7)) << 3)];
            }
            #pragma unroll
            for (int i = 0; i < 2; ++i)
                #pragma unroll
                for (int j = 0; j < 2; ++j)
                    acc[i][j] = __builtin_amdgcn_mfma_f32_16x16x32_bf16(a[i], b[j], acc[i][j], 0, 0, 0);
        }
        __syncthreads();
    }

    #pragma unroll
    for (int i = 0; i < 2; ++i)
        #pragma unroll
        for (int j = 0; j < 2; ++j)
            #pragma unroll
            for (int r = 0; r < 4; ++r) {
                int row = b0 + wr * 32 + i * 16 + ((lane >> 4) << 2) + r;
                int u   = u0 + wc * 32 + j * 16 + (lane & 15);
                out[(size_t)row * 2048 + OFF + u * d + mi] = acc[i][j][r];
            }
}

// ---------------------------------------------------------------------------
extern "C" void kernel_launch(void* const* d_in, const int* in_sizes, int n_in,
                              void* d_out, int out_size, void* d_ws, size_t ws_size,
                              hipStream_t stream) {
    const float* x1   = (const float*)d_in[0];
    const float* x2   = (const float*)d_in[1];
    const float* W1   = (const float*)d_in[2];
    const float* W2   = (const float*)d_in[3];
    const float* Wout = (const float*)d_in[4];
    float* out = (float*)d_out;

    prep_kernel<<<B_N + 768, 256, 0, stream>>>(x1, x2, W1, W2, Wout, out);
    gemm_c_kernel<<<4608, 256, 0, stream>>>();
    middle_kernel<<<1024, 256, 0, stream>>>();
    out_gemm_kernel<<<576, 256, 0, stream>>>(out);
}